// Round 4
// baseline (274.223 us; speedup 1.0000x reference)
//
#include <hip/hip_runtime.h>
#include <math.h>

// Problem: X[16384,64] fp32, W[8192,64] fp32 -> argmin_c ||x-w_c||^2 (int32)
#define EMB     64
#define NTOK    8192
#define NQ      16384
#define TPB     256
#define NSPLIT  8                 // codeword splits -> grid 128x8 = 1024 blocks = 4/CU (LDS-capped)
#define CRANGE  (NTOK / NSPLIT)   // 1024 codewords per block
#define BQ      128               // query rows per block
#define TILE_C  128               // codewords staged in LDS per iteration
#define ROWP    72                // padded LDS row (fp16): 144 B -> uniform 8/bank on b128 reads

typedef _Float16 half8 __attribute__((ext_vector_type(8)));
typedef float    f32x4 __attribute__((ext_vector_type(4)));

// ---------------------------------------------------------------------------
// Prep (fused): per codeword compute ||w||^2, split w -> fp16 hi + lo
// (w ~= wh + wl, residual ~2^-22 rel), and init the packed argmin table.
// ---------------------------------------------------------------------------
__global__ void prep_kernel(const float* __restrict__ W,
                            _Float16* __restrict__ Wh, _Float16* __restrict__ Wl,
                            float* __restrict__ ynorm,
                            unsigned long long* __restrict__ best) {
    int c = blockIdx.x * blockDim.x + threadIdx.x;   // 0..8191
    if (c >= NTOK) return;
    best[c] = ~0ULL;                 // 16384 entries, 8192 threads -> 2 each
    best[c + NTOK] = ~0ULL;
    const float* wp = W + (size_t)c * EMB;
    float s = 0.f;
#pragma unroll
    for (int seg = 0; seg < 8; ++seg) {
        float4 v0 = *(const float4*)(wp + seg * 8);
        float4 v1 = *(const float4*)(wp + seg * 8 + 4);
        float xv[8] = {v0.x, v0.y, v0.z, v0.w, v1.x, v1.y, v1.z, v1.w};
        half8 h, l;
#pragma unroll
        for (int j = 0; j < 8; ++j) {
            s = fmaf(xv[j], xv[j], s);
            _Float16 hh = (_Float16)xv[j];
            h[j] = hh;
            l[j] = (_Float16)(xv[j] - (float)hh);
        }
        *(half8*)(Wh + (size_t)c * EMB + seg * 8) = h;
        *(half8*)(Wl + (size_t)c * EMB + seg * 8) = l;
    }
    ynorm[c] = s;
}

// ---------------------------------------------------------------------------
// Main: fp16 split-MFMA distance + argmin (3-term: ah*bh + ah*bl + al*bh;
// the al*bl term is ~2^-22 rel and dropped).
// Block: 4 waves = 2(q-half: 64 rows) x 2(c-half: 64 cols of the staged 128).
// A (X hi/lo) in registers; W tile (hi/lo) staged in LDS (+8 fp16 row pad).
// MFMA 16x16x32_f16: A[m=lane&15][k=(lane>>4)*8+j]; C col=lane&15,
// row=(lane>>4)*4+reg (measured, learn_hip m89/m91; R3 passed absmax 0).
// Epilogue: per-lane running argmin -> shfl_xor reduce over 16 col-lanes ->
// LDS combine of the 2 c-halves -> one packed-u64 atomicMin per (block,query).
// ---------------------------------------------------------------------------
__global__ __launch_bounds__(TPB, 4) void vq_mfma_kernel(
    const float* __restrict__ X,
    const _Float16* __restrict__ Wh, const _Float16* __restrict__ Wl,
    const float* __restrict__ ynorm,
    unsigned long long* __restrict__ best)
{
    __shared__ _Float16 Lh[TILE_C][ROWP];
    __shared__ _Float16 Ll[TILE_C][ROWP];
    __shared__ float    Lyn[TILE_C];
    __shared__ float    RedV[2][BQ];
    __shared__ int      RedI[2][BQ];

    const int t    = threadIdx.x;
    const int lane = t & 63;
    const int wid  = t >> 6;       // 0..3
    const int wq   = wid & 1;      // q half (0/1)
    const int wy   = wid >> 1;     // c half (0/1)
    const int l15  = lane & 15;
    const int lq   = lane >> 4;    // 0..3

    const int qblk   = blockIdx.x * BQ;
    const int qbase  = qblk + wq * 64;
    const int cbase0 = blockIdx.y * CRANGE;

    // --- A fragments: X rows (qbase + mt*16 + l15), k = kb*32 + lq*8 + j ---
    half8 ah[4][2], al[4][2];
#pragma unroll
    for (int mt = 0; mt < 4; ++mt) {
#pragma unroll
        for (int kb = 0; kb < 2; ++kb) {
            const float* xp = X + (size_t)(qbase + mt * 16 + l15) * EMB + kb * 32 + lq * 8;
            float4 v0 = *(const float4*)xp;
            float4 v1 = *(const float4*)(xp + 4);
            float xv[8] = {v0.x, v0.y, v0.z, v0.w, v1.x, v1.y, v1.z, v1.w};
            half8 h, l;
#pragma unroll
            for (int j = 0; j < 8; ++j) {
                _Float16 hh = (_Float16)xv[j];
                h[j] = hh;
                l[j] = (_Float16)(xv[j] - (float)hh);
            }
            ah[mt][kb] = h;
            al[mt][kb] = l;
        }
    }

    float minv[4][4];
    int   mini[4][4];
#pragma unroll
    for (int mt = 0; mt < 4; ++mt)
#pragma unroll
        for (int r = 0; r < 4; ++r) { minv[mt][r] = INFINITY; mini[mt][r] = 0; }

    const f32x4 zero4 = {0.f, 0.f, 0.f, 0.f};

    for (int c0 = 0; c0 < CRANGE; c0 += TILE_C) {
        const int cb = cbase0 + c0;

        __syncthreads();   // previous-iter LDS reads done before overwrite
        for (int u = t; u < TILE_C * 8; u += TPB) {
            int row = u >> 3, seg = u & 7;
            *(half8*)&Lh[row][seg * 8] = *(const half8*)(Wh + (size_t)(cb + row) * EMB + seg * 8);
            *(half8*)&Ll[row][seg * 8] = *(const half8*)(Wl + (size_t)(cb + row) * EMB + seg * 8);
        }
        if (t < TILE_C / 4) *(float4*)&Lyn[t * 4] = *(const float4*)(ynorm + cb + t * 4);
        __syncthreads();

#pragma unroll
        for (int ct = 0; ct < 4; ++ct) {
            const int ccol = wy * 64 + ct * 16;
            f32x4 acc[4];
            {
                // kb = 0 (k = 0..31): smallest-magnitude terms first
                half8 bh = *(const half8*)&Lh[ccol + l15][lq * 8];
                half8 bl = *(const half8*)&Ll[ccol + l15][lq * 8];
#pragma unroll
                for (int mt = 0; mt < 4; ++mt) {
                    f32x4 a = __builtin_amdgcn_mfma_f32_16x16x32_f16(al[mt][0], bh, zero4, 0, 0, 0);
                    a = __builtin_amdgcn_mfma_f32_16x16x32_f16(ah[mt][0], bl, a, 0, 0, 0);
                    a = __builtin_amdgcn_mfma_f32_16x16x32_f16(ah[mt][0], bh, a, 0, 0, 0);
                    acc[mt] = a;
                }
                // kb = 1 (k = 32..63)
                bh = *(const half8*)&Lh[ccol + l15][32 + lq * 8];
                bl = *(const half8*)&Ll[ccol + l15][32 + lq * 8];
#pragma unroll
                for (int mt = 0; mt < 4; ++mt) {
                    f32x4 a = acc[mt];
                    a = __builtin_amdgcn_mfma_f32_16x16x32_f16(al[mt][1], bh, a, 0, 0, 0);
                    a = __builtin_amdgcn_mfma_f32_16x16x32_f16(ah[mt][1], bl, a, 0, 0, 0);
                    a = __builtin_amdgcn_mfma_f32_16x16x32_f16(ah[mt][1], bh, a, 0, 0, 0);
                    acc[mt] = a;
                }
            }
            // --- dist = ynorm - 2*dot; running argmin (c ascending, strict <) ---
            const float yn   = Lyn[ccol + l15];
            const int   cidx = cb + ccol + l15;
#pragma unroll
            for (int mt = 0; mt < 4; ++mt) {
#pragma unroll
                for (int r = 0; r < 4; ++r) {
                    float s = fmaf(-2.f, acc[mt][r], yn);
                    if (s < minv[mt][r]) { minv[mt][r] = s; mini[mt][r] = cidx; }
                }
            }
        }
    }

    // --- cross-lane: reduce over the 16 col-lanes (xor on low 4 lane bits) ---
#pragma unroll
    for (int mt = 0; mt < 4; ++mt) {
#pragma unroll
        for (int r = 0; r < 4; ++r) {
            float v = minv[mt][r];
            int   i = mini[mt][r];
#pragma unroll
            for (int m = 1; m <= 8; m <<= 1) {
                float ov = __shfl_xor(v, m, 64);
                int   oi = __shfl_xor(i, m, 64);
                if (ov < v || (ov == v && oi < i)) { v = ov; i = oi; }
            }
            if (l15 == 0) {
                int qoff = wq * 64 + mt * 16 + lq * 4 + r;
                RedV[wy][qoff] = v;
                RedI[wy][qoff] = i;
            }
        }
    }
    __syncthreads();

    // --- combine the two c-halves; packed atomicMin (monotone float encode,
    //     idx in low bits -> equal dist resolves to lowest index = first-wins) ---
    if (t < BQ) {
        float v0 = RedV[0][t]; int i0 = RedI[0][t];
        float v1 = RedV[1][t]; int i1 = RedI[1][t];
        if (v1 < v0 || (v1 == v0 && i1 < i0)) { v0 = v1; i0 = i1; }
        unsigned ub = __float_as_uint(v0);
        ub = (ub & 0x80000000u) ? ~ub : (ub | 0x80000000u);
        unsigned long long packed = ((unsigned long long)ub << 32) | (unsigned)i0;
        atomicMin(best + qblk + t, packed);
    }
}

// ---------------------------------------------------------------------------
// Extract: packed u64 -> int32 index
// ---------------------------------------------------------------------------
__global__ void extract_kernel(const unsigned long long* __restrict__ best,
                               int* __restrict__ out)
{
    int q = blockIdx.x * blockDim.x + threadIdx.x;
    if (q >= NQ) return;
    out[q] = (int)(best[q] & 0xFFFFFFFFu);
}

// ---------------------------------------------------------------------------
extern "C" void kernel_launch(void* const* d_in, const int* in_sizes, int n_in,
                              void* d_out, int out_size, void* d_ws, size_t ws_size,
                              hipStream_t stream) {
    const float* X = (const float*)d_in[0];   // [16384, 64]
    const float* W = (const float*)d_in[1];   // [8192, 64]

    // ws layout: Wh(1MB) | Wl(1MB) | ynorm(32KB) | best(128KB)  -> 2.19MB total
    _Float16* Wh    = (_Float16*)d_ws;
    _Float16* Wl    = Wh + (size_t)NTOK * EMB;
    float*    ynorm = (float*)(Wl + (size_t)NTOK * EMB);
    unsigned long long* best = (unsigned long long*)(ynorm + NTOK);
    int*      out   = (int*)d_out;

    prep_kernel<<<NTOK / TPB, TPB, 0, stream>>>(W, Wh, Wl, ynorm, best);
    dim3 grid(NQ / BQ, NSPLIT);
    vq_mfma_kernel<<<grid, TPB, 0, stream>>>(X, Wh, Wl, ynorm, best);
    extract_kernel<<<NQ / TPB, TPB, 0, stream>>>(best, out);
}

// Round 5
// 216.224 us; speedup vs baseline: 1.2682x; 1.2682x over previous
//
#include <hip/hip_runtime.h>
#include <math.h>

// Problem: X[16384,64] fp32, W[8192,64] fp32 -> argmin_c ||x-w_c||^2 (int32)
#define EMB     64
#define NTOK    8192
#define NQ      16384
#define TPB     256
#define NSPLIT  8                 // grid 128x8 = 1024 blocks = 4/CU (LDS-capped)
#define CRANGE  (NTOK / NSPLIT)   // 1024 codewords per block
#define BQ      128               // query rows per block
#define NBLK    ((NQ / BQ) * NSPLIT)   // 1024
#define TILE_C  128               // codewords staged in LDS per iteration
#define ROWP    72                // padded LDS row (fp16): 144 B -> uniform bank spread

typedef _Float16 half8 __attribute__((ext_vector_type(8)));
typedef float    f32x4 __attribute__((ext_vector_type(4)));

// ---------------------------------------------------------------------------
// Prep (fused): per codeword compute ||w||^2, split (-2w) -> fp16 hi + lo
// (-2w ~= wh + wl, residual ~2^-22 rel), init packed argmin table + counter.
// Folding -2 here lets the MFMA accumulator BE the distance (C init = ||w||^2).
// ---------------------------------------------------------------------------
__global__ void prep_kernel(const float* __restrict__ W,
                            _Float16* __restrict__ Wh, _Float16* __restrict__ Wl,
                            float* __restrict__ ynorm,
                            unsigned long long* __restrict__ best,
                            unsigned* __restrict__ counter) {
    int c = blockIdx.x * blockDim.x + threadIdx.x;   // 0..8191
    if (c >= NTOK) return;
    if (c == 0) *counter = 0u;
    best[c] = ~0ULL;                 // 16384 entries, 8192 threads -> 2 each
    best[c + NTOK] = ~0ULL;
    const float* wp = W + (size_t)c * EMB;
    float s = 0.f;
#pragma unroll
    for (int seg = 0; seg < 8; ++seg) {
        float4 v0 = *(const float4*)(wp + seg * 8);
        float4 v1 = *(const float4*)(wp + seg * 8 + 4);
        float xv[8] = {v0.x, v0.y, v0.z, v0.w, v1.x, v1.y, v1.z, v1.w};
        half8 h, l;
#pragma unroll
        for (int j = 0; j < 8; ++j) {
            s = fmaf(xv[j], xv[j], s);
            float m2 = -2.f * xv[j];
            _Float16 hh = (_Float16)m2;
            h[j] = hh;
            l[j] = (_Float16)(m2 - (float)hh);
        }
        *(half8*)(Wh + (size_t)c * EMB + seg * 8) = h;
        *(half8*)(Wl + (size_t)c * EMB + seg * 8) = l;
    }
    ynorm[c] = s;
}

// ---------------------------------------------------------------------------
// Main: fp16 split-MFMA distance + argmin (3-term: ah*bh + ah*bl + al*bh with
// B = split(-2w); the al*bl term is ~2^-22 rel and dropped).
// Block: 4 waves = 2(q-half: 64 rows) x 2(c-half: 64 cols of the staged 128).
// A (X hi/lo) in registers; B tile (hi/lo) staged in LDS (+8 fp16 row pad).
// MFMA 16x16x32_f16: A[m=lane&15][k=(lane>>4)*8+j]; C col=lane&15,
// row=(lane>>4)*4+reg (measured, learn_hip m89/m91; R3/R4 passed absmax 0).
// C initialized to ||w_c||^2 (col-only dependence -> free splat) so the
// accumulator directly holds dist = ||w||^2 - 2 x.w.
// Epilogue: per-lane running argmin -> shfl_xor over 16 col-lanes -> LDS
// combine of 2 c-halves -> one packed-u64 atomicMin per (block,query).
// Tail: last-done block extracts best[] -> int32 out (device-scope loads).
// NOTE: launch_bounds MUST stay (256,3): (256,4) snaps the VGPR budget to 64
// and spills the 64-VGPR A-fragment set to scratch (R4: 900 MB HBM, 2x slower).
// ---------------------------------------------------------------------------
__global__ __launch_bounds__(TPB, 3) void vq_mfma_kernel(
    const float* __restrict__ X,
    const _Float16* __restrict__ Wh, const _Float16* __restrict__ Wl,
    const float* __restrict__ ynorm,
    unsigned long long* __restrict__ best,
    unsigned* __restrict__ counter,
    int* __restrict__ out)
{
    __shared__ _Float16 Lh[TILE_C][ROWP];
    __shared__ _Float16 Ll[TILE_C][ROWP];
    __shared__ float    Lyn[TILE_C];
    __shared__ float    RedV[2][BQ];
    __shared__ int      RedI[2][BQ];
    __shared__ int      lastFlag;

    const int t    = threadIdx.x;
    const int lane = t & 63;
    const int wid  = t >> 6;       // 0..3
    const int wq   = wid & 1;      // q half (0/1)
    const int wy   = wid >> 1;     // c half (0/1)
    const int l15  = lane & 15;
    const int lq   = lane >> 4;    // 0..3

    const int qblk   = blockIdx.x * BQ;
    const int qbase  = qblk + wq * 64;
    const int cbase0 = blockIdx.y * CRANGE;

    // --- A fragments: X rows (qbase + mt*16 + l15), k = kb*32 + lq*8 + j ---
    half8 ah[4][2], al[4][2];
#pragma unroll
    for (int mt = 0; mt < 4; ++mt) {
#pragma unroll
        for (int kb = 0; kb < 2; ++kb) {
            const float* xp = X + (size_t)(qbase + mt * 16 + l15) * EMB + kb * 32 + lq * 8;
            float4 v0 = *(const float4*)xp;
            float4 v1 = *(const float4*)(xp + 4);
            float xv[8] = {v0.x, v0.y, v0.z, v0.w, v1.x, v1.y, v1.z, v1.w};
            half8 h, l;
#pragma unroll
            for (int j = 0; j < 8; ++j) {
                _Float16 hh = (_Float16)xv[j];
                h[j] = hh;
                l[j] = (_Float16)(xv[j] - (float)hh);
            }
            ah[mt][kb] = h;
            al[mt][kb] = l;
        }
    }

    float minv[4][4];
    int   mini[4][4];
#pragma unroll
    for (int mt = 0; mt < 4; ++mt)
#pragma unroll
        for (int r = 0; r < 4; ++r) { minv[mt][r] = INFINITY; mini[mt][r] = 0; }

    for (int c0 = 0; c0 < CRANGE; c0 += TILE_C) {
        const int cb = cbase0 + c0;

        __syncthreads();   // previous-iter LDS reads done before overwrite
        for (int u = t; u < TILE_C * 8; u += TPB) {
            int row = u >> 3, seg = u & 7;
            *(half8*)&Lh[row][seg * 8] = *(const half8*)(Wh + (size_t)(cb + row) * EMB + seg * 8);
            *(half8*)&Ll[row][seg * 8] = *(const half8*)(Wl + (size_t)(cb + row) * EMB + seg * 8);
        }
        if (t < TILE_C / 4) *(float4*)&Lyn[t * 4] = *(const float4*)(ynorm + cb + t * 4);
        __syncthreads();

#pragma unroll
        for (int ct = 0; ct < 4; ++ct) {
            const int ccol = wy * 64 + ct * 16;
            const float yn = Lyn[ccol + l15];          // this lane's col norm
            const f32x4 cinit = {yn, yn, yn, yn};      // C layout: col = lane&15 for all regs
            f32x4 acc[4];
            {
                // kb = 0 (k = 0..31): smaller-magnitude terms first
                half8 bh = *(const half8*)&Lh[ccol + l15][lq * 8];
                half8 bl = *(const half8*)&Ll[ccol + l15][lq * 8];
#pragma unroll
                for (int mt = 0; mt < 4; ++mt) {
                    f32x4 a = __builtin_amdgcn_mfma_f32_16x16x32_f16(al[mt][0], bh, cinit, 0, 0, 0);
                    a = __builtin_amdgcn_mfma_f32_16x16x32_f16(ah[mt][0], bl, a, 0, 0, 0);
                    a = __builtin_amdgcn_mfma_f32_16x16x32_f16(ah[mt][0], bh, a, 0, 0, 0);
                    acc[mt] = a;
                }
                // kb = 1 (k = 32..63)
                bh = *(const half8*)&Lh[ccol + l15][32 + lq * 8];
                bl = *(const half8*)&Ll[ccol + l15][32 + lq * 8];
#pragma unroll
                for (int mt = 0; mt < 4; ++mt) {
                    f32x4 a = acc[mt];
                    a = __builtin_amdgcn_mfma_f32_16x16x32_f16(al[mt][1], bh, a, 0, 0, 0);
                    a = __builtin_amdgcn_mfma_f32_16x16x32_f16(ah[mt][1], bl, a, 0, 0, 0);
                    a = __builtin_amdgcn_mfma_f32_16x16x32_f16(ah[mt][1], bh, a, 0, 0, 0);
                    acc[mt] = a;
                }
            }
            // --- acc IS the distance; running argmin (c ascending, strict <) ---
            const int cidx = cb + ccol + l15;
#pragma unroll
            for (int mt = 0; mt < 4; ++mt) {
#pragma unroll
                for (int r = 0; r < 4; ++r) {
                    float s = acc[mt][r];
                    if (s < minv[mt][r]) { minv[mt][r] = s; mini[mt][r] = cidx; }
                }
            }
        }
    }

    // --- cross-lane: reduce over the 16 col-lanes (xor on low 4 lane bits) ---
#pragma unroll
    for (int mt = 0; mt < 4; ++mt) {
#pragma unroll
        for (int r = 0; r < 4; ++r) {
            float v = minv[mt][r];
            int   i = mini[mt][r];
#pragma unroll
            for (int m = 1; m <= 8; m <<= 1) {
                float ov = __shfl_xor(v, m, 64);
                int   oi = __shfl_xor(i, m, 64);
                if (ov < v || (ov == v && oi < i)) { v = ov; i = oi; }
            }
            if (l15 == 0) {
                int qoff = wq * 64 + mt * 16 + lq * 4 + r;
                RedV[wy][qoff] = v;
                RedI[wy][qoff] = i;
            }
        }
    }
    __syncthreads();

    // --- combine halves; packed atomicMin (monotone float encode, idx in low
    //     bits -> equal dist resolves to lowest index = first-wins) ---
    if (t < BQ) {
        float v0 = RedV[0][t]; int i0 = RedI[0][t];
        float v1 = RedV[1][t]; int i1 = RedI[1][t];
        if (v1 < v0 || (v1 == v0 && i1 < i0)) { v0 = v1; i0 = i1; }
        unsigned ub = __float_as_uint(v0);
        ub = (ub & 0x80000000u) ? ~ub : (ub | 0x80000000u);
        unsigned long long packed = ((unsigned long long)ub << 32) | (unsigned)i0;
        atomicMin(best + qblk + t, packed);
    }

    // --- last-done block extracts indices (saves a kernel launch) ---
    __threadfence();                       // release best[] updates, device scope
    if (t == 0) {
        unsigned done = __hip_atomic_fetch_add(counter, 1u, __ATOMIC_ACQ_REL,
                                               __HIP_MEMORY_SCOPE_AGENT);
        lastFlag = (done == NBLK - 1) ? 1 : 0;
    }
    __syncthreads();
    if (lastFlag) {
        for (int q = t; q < NQ; q += TPB) {
            unsigned long long p = __hip_atomic_load(best + q, __ATOMIC_RELAXED,
                                                     __HIP_MEMORY_SCOPE_AGENT);
            out[q] = (int)(p & 0xFFFFFFFFu);
        }
    }
}

// ---------------------------------------------------------------------------
extern "C" void kernel_launch(void* const* d_in, const int* in_sizes, int n_in,
                              void* d_out, int out_size, void* d_ws, size_t ws_size,
                              hipStream_t stream) {
    const float* X = (const float*)d_in[0];   // [16384, 64]
    const float* W = (const float*)d_in[1];   // [8192, 64]

    // ws layout: Wh(1MB) | Wl(1MB) | ynorm(32KB) | best(128KB) | counter
    _Float16* Wh    = (_Float16*)d_ws;
    _Float16* Wl    = Wh + (size_t)NTOK * EMB;
    float*    ynorm = (float*)(Wl + (size_t)NTOK * EMB);
    unsigned long long* best = (unsigned long long*)(ynorm + NTOK);
    unsigned* counter = (unsigned*)(best + NQ);
    int*      out   = (int*)d_out;

    prep_kernel<<<NTOK / TPB, TPB, 0, stream>>>(W, Wh, Wl, ynorm, best, counter);
    dim3 grid(NQ / BQ, NSPLIT);
    vq_mfma_kernel<<<grid, TPB, 0, stream>>>(X, Wh, Wl, ynorm, best, counter, out);
}